// Round 9
// baseline (109.919 us; speedup 1.0000x reference)
//
#include <hip/hip_runtime.h>
#include <hip/hip_fp16.h>

typedef _Float16 f16x8 __attribute__((ext_vector_type(8)));
typedef _Float16 f16x4 __attribute__((ext_vector_type(4)));
typedef float f32x4 __attribute__((ext_vector_type(4)));

#define D_MODEL 1024
#define SEQ 1024
#define BATCH 4
#define NH 16
#define DV 64
#define M_TOTAL (BATCH * SEQ)   // 4096
#define QBLK 128

__device__ __forceinline__ void gload16(const _Float16* g, _Float16* lds) {
    __builtin_amdgcn_global_load_lds((const __attribute__((address_space(1))) void*)g,
                                     (__attribute__((address_space(3))) void*)lds,
                                     16, 0, 0);
}

__device__ __forceinline__ unsigned pk16(float a, float b) {
    auto h = __builtin_amdgcn_cvt_pkrtz(a, b);   // __fp16 ext_vector_type(2)
    unsigned r;
    __builtin_memcpy(&r, &h, 4);
    return r;
}

// ---------------- fp32 -> fp16 convert (8 elems/thread) ----------------
__global__ void cvt_f32_f16(const float* __restrict__ s, _Float16* __restrict__ d, int n) {
    int i = (blockIdx.x * blockDim.x + threadIdx.x) * 8;
    if (i >= n) return;
    float4 a = *(const float4*)(s + i);
    float4 b = *(const float4*)(s + i + 4);
    f16x8 h;
    h[0] = (_Float16)a.x; h[1] = (_Float16)a.y; h[2] = (_Float16)a.z; h[3] = (_Float16)a.w;
    h[4] = (_Float16)b.x; h[5] = (_Float16)b.y; h[6] = (_Float16)b.z; h[7] = (_Float16)b.w;
    *(f16x8*)(d + i) = h;
}

__global__ void cvt3_f32_f16(const float* __restrict__ s0, const float* __restrict__ s1,
                             const float* __restrict__ s2, _Float16* __restrict__ d0,
                             _Float16* __restrict__ d1, _Float16* __restrict__ d2, int n) {
    const float* s = (blockIdx.y == 0) ? s0 : (blockIdx.y == 1 ? s1 : s2);
    _Float16*    d = (blockIdx.y == 0) ? d0 : (blockIdx.y == 1 ? d1 : d2);
    int i = (blockIdx.x * blockDim.x + threadIdx.x) * 8;
    if (i >= n) return;
    float4 a = *(const float4*)(s + i);
    float4 b = *(const float4*)(s + i + 4);
    f16x8 h;
    h[0] = (_Float16)a.x; h[1] = (_Float16)a.y; h[2] = (_Float16)a.z; h[3] = (_Float16)a.w;
    h[4] = (_Float16)b.x; h[5] = (_Float16)b.y; h[6] = (_Float16)b.z; h[7] = (_Float16)b.w;
    *(f16x8*)(d + i) = h;
}

// ---------------- fused QKV projection GEMM: 256x256 8-phase (unchanged, known-good) ----------------
__global__ __launch_bounds__(512, 2) void qkv_gemm(
    const _Float16* __restrict__ X,
    const _Float16* __restrict__ W0, const _Float16* __restrict__ W1, const _Float16* __restrict__ W2,
    const float* __restrict__ b0, const float* __restrict__ b1, const float* __restrict__ b2,
    _Float16* __restrict__ Qo, _Float16* __restrict__ Ko, _Float16* __restrict__ Vto)
{
    __shared__ _Float16 SM[4 * 256 * 64];   // A dbuf | B dbuf; reused as 256x256 EP scratch
#define ABASE(buf) (SM + (buf) * 16384)
#define BBASE(buf) (SM + 32768 + (buf) * 16384)

    const int tid = threadIdx.x;
    const int l = tid & 63;
    const int w = tid >> 6;
    const int wr = w >> 2, wc = w & 3;

    const int bid = blockIdx.x;
    const int nid = (bid & 7) * 24 + (bid >> 3);
    const int mt = nid & 15, ntg = nid >> 4;
    const int mat = ntg >> 2, nt = ntg & 3;       // mat: 0=Q 1=K 2=V
    const _Float16* Wm  = (mat == 0) ? W0 : (mat == 1 ? W1 : W2);
    const float*    bia = (mat == 0) ? b0 : (mat == 1 ? b1 : b2);
    const int m0 = mt * 256, n0 = nt * 256;

    const int str = tid >> 3;
    const int sc8 = ((tid & 7) ^ (str & 7)) * 8;
    const _Float16* xsrc = X  + (size_t)(m0 + str) * D_MODEL + sc8;
    const _Float16* wsrc = Wm + (size_t)(n0 + str) * D_MODEL + sc8;
    const int ldst = str * 64 + (tid & 7) * 8;

#define SA(buf, kt, h) do { \
    gload16(xsrc + (size_t)((h) * 128) * D_MODEL + (kt) * 64, ABASE(buf) + (h) * 8192 + ldst); \
    gload16(xsrc + (size_t)((h) * 128 + 64) * D_MODEL + (kt) * 64, ABASE(buf) + (h) * 8192 + 4096 + ldst); } while (0)
#define SB(buf, kt, h) do { \
    gload16(wsrc + (size_t)((h) * 128) * D_MODEL + (kt) * 64, BBASE(buf) + (h) * 8192 + ldst); \
    gload16(wsrc + (size_t)((h) * 128 + 64) * D_MODEL + (kt) * 64, BBASE(buf) + (h) * 8192 + 4096 + ldst); } while (0)

    const int fr = l & 15, g = l >> 4, fr7 = l & 7;
    const int wrow = wr * 128, bcol = wc * 64;

    f32x4 acc[8][4] = {};
    f16x8 b[4][2];

    SB(0, 0, 0); SB(0, 0, 1);
    SA(0, 0, 0); SA(0, 0, 1);
    SB(1, 1, 0); SB(1, 1, 1);
    asm volatile("s_waitcnt vmcnt(4)" ::: "memory");
    __builtin_amdgcn_s_barrier();

#define PHASES(BUF, TSA_BUF, TSA, TSB_BUF, TSB)                                              \
    _Pragma("unroll")                                                                        \
    for (int p = 0; p < 4; ++p) {                                                            \
        if (p == 0) {                                                                        \
            _Pragma("unroll")                                                                \
            for (int nj = 0; nj < 4; ++nj) {                                                 \
                const int rb = (bcol + nj * 16 + fr) * 64;                                   \
                b[nj][0] = *(const f16x8*)&BBASE(BUF)[rb + ((g ^ fr7) << 3)];                \
                b[nj][1] = *(const f16x8*)&BBASE(BUF)[rb + (((4 + g) ^ fr7) << 3)];          \
            }                                                                                \
        }                                                                                    \
        f16x8 aq[2][2];                                                                      \
        _Pragma("unroll")                                                                    \
        for (int q = 0; q < 2; ++q) {                                                        \
            const int ra = (wrow + (2 * p + q) * 16 + fr) * 64;                              \
            aq[q][0] = *(const f16x8*)&ABASE(BUF)[ra + ((g ^ fr7) << 3)];                    \
            aq[q][1] = *(const f16x8*)&ABASE(BUF)[ra + (((4 + g) ^ fr7) << 3)];              \
        }                                                                                    \
        if (p == 0) SA(TSA_BUF, TSA, 0);                                                     \
        else if (p == 1) SA(TSA_BUF, TSA, 1);                                                \
        else if (p == 2) SB(TSB_BUF, TSB, 0);                                                \
        else SB(TSB_BUF, TSB, 1);                                                            \
        __builtin_amdgcn_s_barrier();                                                        \
        __builtin_amdgcn_s_setprio(1);                                                       \
        _Pragma("unroll")                                                                    \
        for (int ks = 0; ks < 2; ++ks)                                                       \
            _Pragma("unroll")                                                                \
            for (int q = 0; q < 2; ++q)                                                      \
                _Pragma("unroll")                                                            \
                for (int nj = 0; nj < 4; ++nj)                                               \
                    acc[2 * p + q][nj] = __builtin_amdgcn_mfma_f32_16x16x32_f16(             \
                        aq[q][ks], b[nj][ks], acc[2 * p + q][nj], 0, 0, 0);                  \
        __builtin_amdgcn_s_setprio(0);                                                       \
        if (p == 3) asm volatile("s_waitcnt vmcnt(4)" ::: "memory");                         \
        __builtin_amdgcn_s_barrier();                                                        \
    }

    for (int it = 0; it < 8; ++it) {
        const int tA = 2 * it + 1;
        const int tN = (2 * it + 2 < 16) ? 2 * it + 2 : 15;
        const int tM = (2 * it + 3 < 16) ? 2 * it + 3 : 15;
        PHASES(0, 1, tA, 0, tN)
        PHASES(1, 0, tN, 1, tM)
    }
#undef PHASES
#undef SA
#undef SB

    if (mat != 2) {
        const float scale = (mat == 0) ? 0.125f * 1.44269504088896340736f : 1.0f;
#pragma unroll
        for (int nj = 0; nj < 4; ++nj) {
            const int o = n0 + bcol + nj * 16 + fr;
            const float bb = bia[o];
            const int h = o >> 6, dd = o & 63;
#pragma unroll
            for (int mi = 0; mi < 8; ++mi) {
#pragma unroll
                for (int r = 0; r < 4; ++r) {
                    const int m = m0 + wrow + mi * 16 + g * 4 + r;
                    const int bi = m >> 10, s = m & 1023;
                    const float v = (acc[mi][nj][r] + bb) * scale;
                    const _Float16 hv = (_Float16)v;
                    const int bh = bi * NH + h;
                    if (mat == 0) Qo[((size_t)bh * SEQ + s) * DV + dd] = hv;
                    else          Ko[((size_t)bh * SEQ + s) * DV + dd] = hv;
                }
            }
        }
    } else {
        // V epilogue via LDS: transpose + coalesced 16B stores
        asm volatile("s_waitcnt vmcnt(0)" ::: "memory");
        __syncthreads();
#pragma unroll
        for (int nj = 0; nj < 4; ++nj) {
            const int n = bcol + nj * 16 + fr;
            const float bb = bia[n0 + n];
#pragma unroll
            for (int mi = 0; mi < 8; ++mi) {
#pragma unroll
                for (int r = 0; r < 4; ++r) {
                    const int m = wrow + mi * 16 + g * 4 + r;
                    SM[n * 256 + ((((m >> 3) + n) & 31) << 3) + (m & 7)] =
                        (_Float16)(acc[mi][nj][r] + bb);
                }
            }
        }
        __syncthreads();
        const int bi = m0 >> 10, s0 = m0 & 1023;
#pragma unroll
        for (int itp = 0; itp < 16; ++itp) {
            const int task = itp * 512 + tid;
            const int dd = task >> 5, sc = task & 31;
            f16x8 vv = *(const f16x8*)&SM[dd * 256 + (((sc + dd) & 31) << 3)];
            const int og = n0 + dd;
            const int h = og >> 6, d = og & 63;
            const int bh = bi * NH + h;
            *(f16x8*)(Vto + ((size_t)bh * DV + d) * SEQ + s0 + sc * 8) = vv;
        }
    }
#undef ABASE
#undef BBASE
}

// ---------------- flash attention v4: LDS-free, direct-from-L2 K/V ----------------
// K/V per head = 256KB, L2-resident per XCD (FETCH confirms). No LDS, no barriers:
// every wave is fully independent -> no 2-phase drain stall. 4 waves/block, 32 q-rows
// per wave (each K/V fragment feeds 2 MFMAs). In-wave pipeline: V(t) issued at body
// top (consumed after QK+softmax), K(t+1) prefetched into alternate reg set before
// softmax (consumed next body). In-register P via pk16 + shfl_xor butterfly (r8-verified).
__global__ __launch_bounds__(256, 2) void attn(
    const _Float16* __restrict__ Q, const _Float16* __restrict__ K,
    const _Float16* __restrict__ Vt, float* __restrict__ out)
{
    const int tid = threadIdx.x;
    const int w = tid >> 6, l = tid & 63;
    const int qc = l & 15, g = l >> 4;
    const int g0 = g & 1, g1 = g >> 1;

    // XCD swizzle: all 8 q-tiles of a head land on one XCD (512 % 8 == 0, bijective)
    const int fid = blockIdx.y * 8 + blockIdx.x;        // grid = (8, 64)
    const int nid = (fid & 7) * 64 + (fid >> 3);
    const int bh = nid >> 3, qt = nid & 7;
    const int b = bh >> 4, h = bh & 15;
    const int q0 = qt * QBLK + w * 32;

    const _Float16* Kg = K  + (size_t)bh * SEQ * DV;
    const _Float16* Vg = Vt + (size_t)bh * DV * SEQ;

    f16x8 qf[2][2];
#pragma unroll
    for (int qg = 0; qg < 2; ++qg) {
        const _Float16* qp = Q + ((size_t)bh * SEQ + q0 + qg * 16 + qc) * DV + g * 8;
        qf[qg][0] = *(const f16x8*)(qp);
        qf[qg][1] = *(const f16x8*)(qp + 32);
    }

    float m_run[2] = {-1e30f, -1e30f}, l_run[2] = {0.f, 0.f};
    f32x4 oacc[2][4] = {};

    f16x8 kA[8], kB[8];   // double-buffered K fragments (named sets, static indexing)
#pragma unroll
    for (int kf = 0; kf < 4; ++kf) {
        const _Float16* kp = Kg + (size_t)(kf * 16 + qc) * DV + g * 8;
        kA[kf * 2]     = *(const f16x8*)(kp);
        kA[kf * 2 + 1] = *(const f16x8*)(kp + 32);
    }

#define ABODY(KC, KN, t)                                                                     \
    {                                                                                        \
        const int kb = (t) * 64;                                                             \
        /* V loads for tile t: latency covered by QK + softmax */                            \
        f16x8 vr[2][4];                                                                      \
        _Pragma("unroll")                                                                    \
        for (int ks = 0; ks < 2; ++ks)                                                       \
            _Pragma("unroll")                                                                \
            for (int df = 0; df < 4; ++df)                                                   \
                vr[ks][df] = *(const f16x8*)(Vg + (size_t)(df * 16 + qc) * SEQ + kb +        \
                                             ks * 32 + g * 8);                               \
        /* QK^T (swapped), K regs ready from previous body */                                \
        f32x4 sT[2][4];                                                                      \
        const f32x4 zf = {0.f, 0.f, 0.f, 0.f};                                               \
        __builtin_amdgcn_s_setprio(1);                                                       \
        _Pragma("unroll")                                                                    \
        for (int kf = 0; kf < 4; ++kf)                                                       \
            _Pragma("unroll")                                                                \
            for (int qg = 0; qg < 2; ++qg) {                                                 \
                f32x4 tt = __builtin_amdgcn_mfma_f32_16x16x32_f16(KC[2 * kf], qf[qg][0],     \
                                                                  zf, 0, 0, 0);             \
                sT[qg][kf] = __builtin_amdgcn_mfma_f32_16x16x32_f16(KC[2 * kf + 1],          \
                                                                    qf[qg][1], tt, 0, 0, 0); \
            }                                                                                \
        __builtin_amdgcn_s_setprio(0);                                                       \
        /* K prefetch for tile t+1 (clamped; latency covered by softmax+PV) */               \
        const int tn = ((t) + 1 < 16) ? (t) + 1 : 15;                                        \
        _Pragma("unroll")                                                                    \
        for (int kf = 0; kf < 4; ++kf) {                                                     \
            const _Float16* kp = Kg + (size_t)(tn * 64 + kf * 16 + qc) * DV + g * 8;         \
            KN[kf * 2]     = *(const f16x8*)(kp);                                            \
            KN[kf * 2 + 1] = *(const f16x8*)(kp + 32);                                       \
        }                                                                                    \
        /* softmax + in-register P exchange */                                               \
        f16x8 pb[2][2];                                                                      \
        _Pragma("unroll")                                                                    \
        for (int qg = 0; qg < 2; ++qg) {                                                     \
            f32x4 mx = sT[qg][0];                                                            \
            _Pragma("unroll")                                                                \
            for (int kf = 1; kf < 4; ++kf)                                                   \
                _Pragma("unroll")                                                            \
                for (int r = 0; r < 4; ++r) mx[r] = fmaxf(mx[r], sT[qg][kf][r]);             \
            float pmax = fmaxf(fmaxf(mx[0], mx[1]), fmaxf(mx[2], mx[3]));                    \
            pmax = fmaxf(pmax, __shfl_xor(pmax, 16));                                        \
            pmax = fmaxf(pmax, __shfl_xor(pmax, 32));                                        \
            if (!__all(pmax - m_run[qg] <= 8.0f)) {                                          \
                const float mn = fmaxf(m_run[qg], pmax);                                     \
                const float al = exp2f(m_run[qg] - mn);                                      \
                l_run[qg] *= al;                                                             \
                _Pragma("unroll")                                                            \
                for (int df = 0; df < 4; ++df) oacc[qg][df] *= al;                           \
                m_run[qg] = mn;                                                              \
            }                                                                                \
            float rsum = 0.f;                                                                \
            unsigned u[4][2];                                                                \
            _Pragma("unroll")                                                                \
            for (int kf = 0; kf < 4; ++kf) {                                                 \
                const float p0 = exp2f(sT[qg][kf][0] - m_run[qg]);                           \
                const float p1 = exp2f(sT[qg][kf][1] - m_run[qg]);                           \
                const float p2 = exp2f(sT[qg][kf][2] - m_run[qg]);                           \
                const float p3 = exp2f(sT[qg][kf][3] - m_run[qg]);                           \
                rsum += (p0 + p1) + (p2 + p3);                                               \
                u[kf][0] = pk16(p0, p1);                                                     \
                u[kf][1] = pk16(p2, p3);                                                     \
            }                                                                                \
            rsum += __shfl_xor(rsum, 16);                                                    \
            rsum += __shfl_xor(rsum, 32);                                                    \
            l_run[qg] += rsum;                                                               \
            unsigned keep[2][2], rec[2][2];                                                  \
            _Pragma("unroll")                                                                \
            for (int ks = 0; ks < 2; ++ks)                                                   \
                _Pragma("unroll")                                                            \
                for (int rp = 0; rp < 2; ++rp) {                                             \
                    const unsigned own0  = g1 ? u[2 * ks + 1][rp] : u[2 * ks][rp];           \
                    const unsigned send1 = g1 ? u[2 * ks][rp]     : u[2 * ks + 1][rp];       \
                    const unsigned recv0 = (unsigned)__shfl_xor((int)send1, 32);             \
                    const unsigned km = (g1 == g0) ? own0 : recv0;                           \
                    const unsigned sp = (g1 == g0) ? recv0 : own0;                           \
                    rec[ks][rp] = (unsigned)__shfl_xor((int)sp, 16);                         \
                    keep[ks][rp] = km;                                                       \
                }                                                                            \
            _Pragma("unroll")                                                                \
            for (int ks = 0; ks < 2; ++ks) {                                                 \
                unsigned wd[4];                                                              \
                wd[0] = g0 ? rec[ks][0]  : keep[ks][0];                                      \
                wd[1] = g0 ? rec[ks][1]  : keep[ks][1];                                      \
                wd[2] = g0 ? keep[ks][0] : rec[ks][0];                                       \
                wd[3] = g0 ? keep[ks][1] : rec[ks][1];                                       \
                __builtin_memcpy(&pb[qg][ks], wd, 16);                                       \
            }                                                                                \
        }                                                                                    \
        /* PV (transposed), V from regs */                                                   \
        __builtin_amdgcn_s_setprio(1);                                                       \
        _Pragma("unroll")                                                                    \
        for (int ks = 0; ks < 2; ++ks)                                                       \
            _Pragma("unroll")                                                                \
            for (int df = 0; df < 4; ++df) {                                                 \
                oacc[0][df] = __builtin_amdgcn_mfma_f32_16x16x32_f16(vr[ks][df], pb[0][ks],  \
                                                                     oacc[0][df], 0, 0, 0);  \
                oacc[1][df] = __builtin_amdgcn_mfma_f32_16x16x32_f16(vr[ks][df], pb[1][ks],  \
                                                                     oacc[1][df], 0, 0, 0);  \
            }                                                                                \
        __builtin_amdgcn_s_setprio(0);                                                       \
    }

    for (int kt2 = 0; kt2 < 8; ++kt2) {
        ABODY(kA, kB, 2 * kt2)
        ABODY(kB, kA, 2 * kt2 + 1)
    }
#undef ABODY

#pragma unroll
    for (int qg = 0; qg < 2; ++qg) {
        const float inv = 1.0f / l_run[qg];
        float* op = out + ((size_t)b * SEQ + q0 + qg * 16 + qc) * D_MODEL + h * DV;
#pragma unroll
        for (int df = 0; df < 4; ++df) {
            f32x4 r = oacc[qg][df] * inv;
            float4 v4;
            v4.x = r[0]; v4.y = r[1]; v4.z = r[2]; v4.w = r[3];
            *(float4*)(op + df * 16 + g * 4) = v4;
        }
    }
}

extern "C" void kernel_launch(void* const* d_in, const int* in_sizes, int n_in,
                              void* d_out, int out_size, void* d_ws, size_t ws_size,
                              hipStream_t stream) {
    const float* seq = (const float*)d_in[0];
    const float* Wq  = (const float*)d_in[1];
    const float* bq  = (const float*)d_in[2];
    const float* Wk  = (const float*)d_in[3];
    const float* bk  = (const float*)d_in[4];
    const float* Wv  = (const float*)d_in[5];
    const float* bv  = (const float*)d_in[6];
    float* out = (float*)d_out;

    _Float16* seqh = (_Float16*)d_ws;
    _Float16* wqh  = seqh + (size_t)M_TOTAL * D_MODEL;
    _Float16* wkh  = wqh + (size_t)D_MODEL * D_MODEL;
    _Float16* wvh  = wkh + (size_t)D_MODEL * D_MODEL;
    _Float16* Qh   = wvh + (size_t)D_MODEL * D_MODEL;
    _Float16* Kh   = Qh + (size_t)M_TOTAL * D_MODEL;
    _Float16* Vth  = Kh + (size_t)M_TOTAL * D_MODEL;

    const int n_seq = M_TOTAL * D_MODEL;
    const int n_w   = D_MODEL * D_MODEL;
    cvt_f32_f16<<<n_seq / (256 * 8), 256, 0, stream>>>(seq, seqh, n_seq);
    cvt3_f32_f16<<<dim3(n_w / (256 * 8), 3), 256, 0, stream>>>(Wq, Wk, Wv, wqh, wkh, wvh, n_w);

    qkv_gemm<<<192, 512, 0, stream>>>(
        seqh, wqh, wkh, wvh, bq, bk, bv, Qh, Kh, Vth);

    attn<<<dim3(SEQ / QBLK, BATCH * NH), 256, 0, stream>>>(Qh, Kh, Vth, out);
}

// Round 10
// 82.455 us; speedup vs baseline: 1.3331x; 1.3331x over previous
//
#include <hip/hip_runtime.h>
#include <hip/hip_fp16.h>

typedef _Float16 f16x8 __attribute__((ext_vector_type(8)));
typedef _Float16 f16x4 __attribute__((ext_vector_type(4)));
typedef float f32x4 __attribute__((ext_vector_type(4)));

#define D_MODEL 1024
#define SEQ 1024
#define BATCH 4
#define NH 16
#define DV 64
#define M_TOTAL (BATCH * SEQ)   // 4096
#define QBLK 128

__device__ __forceinline__ void gload16(const _Float16* g, _Float16* lds) {
    __builtin_amdgcn_global_load_lds((const __attribute__((address_space(1))) void*)g,
                                     (__attribute__((address_space(3))) void*)lds,
                                     16, 0, 0);
}

// ---------------- fp32 -> fp16 convert (8 elems/thread) ----------------
__global__ void cvt_f32_f16(const float* __restrict__ s, _Float16* __restrict__ d, int n) {
    int i = (blockIdx.x * blockDim.x + threadIdx.x) * 8;
    if (i >= n) return;
    float4 a = *(const float4*)(s + i);
    float4 b = *(const float4*)(s + i + 4);
    f16x8 h;
    h[0] = (_Float16)a.x; h[1] = (_Float16)a.y; h[2] = (_Float16)a.z; h[3] = (_Float16)a.w;
    h[4] = (_Float16)b.x; h[5] = (_Float16)b.y; h[6] = (_Float16)b.z; h[7] = (_Float16)b.w;
    *(f16x8*)(d + i) = h;
}

__global__ void cvt3_f32_f16(const float* __restrict__ s0, const float* __restrict__ s1,
                             const float* __restrict__ s2, _Float16* __restrict__ d0,
                             _Float16* __restrict__ d1, _Float16* __restrict__ d2, int n) {
    const float* s = (blockIdx.y == 0) ? s0 : (blockIdx.y == 1 ? s1 : s2);
    _Float16*    d = (blockIdx.y == 0) ? d0 : (blockIdx.y == 1 ? d1 : d2);
    int i = (blockIdx.x * blockDim.x + threadIdx.x) * 8;
    if (i >= n) return;
    float4 a = *(const float4*)(s + i);
    float4 b = *(const float4*)(s + i + 4);
    f16x8 h;
    h[0] = (_Float16)a.x; h[1] = (_Float16)a.y; h[2] = (_Float16)a.z; h[3] = (_Float16)a.w;
    h[4] = (_Float16)b.x; h[5] = (_Float16)b.y; h[6] = (_Float16)b.z; h[7] = (_Float16)b.w;
    *(f16x8*)(d + i) = h;
}

// ---------------- fused QKV projection GEMM: 256x256 8-phase (unchanged, known-good) ----------------
__global__ __launch_bounds__(512, 2) void qkv_gemm(
    const _Float16* __restrict__ X,
    const _Float16* __restrict__ W0, const _Float16* __restrict__ W1, const _Float16* __restrict__ W2,
    const float* __restrict__ b0, const float* __restrict__ b1, const float* __restrict__ b2,
    _Float16* __restrict__ Qo, _Float16* __restrict__ Ko, _Float16* __restrict__ Vto)
{
    __shared__ _Float16 SM[4 * 256 * 64];   // A dbuf | B dbuf; reused as 256x256 EP scratch
#define ABASE(buf) (SM + (buf) * 16384)
#define BBASE(buf) (SM + 32768 + (buf) * 16384)

    const int tid = threadIdx.x;
    const int l = tid & 63;
    const int w = tid >> 6;
    const int wr = w >> 2, wc = w & 3;

    const int bid = blockIdx.x;
    const int nid = (bid & 7) * 24 + (bid >> 3);
    const int mt = nid & 15, ntg = nid >> 4;
    const int mat = ntg >> 2, nt = ntg & 3;       // mat: 0=Q 1=K 2=V
    const _Float16* Wm  = (mat == 0) ? W0 : (mat == 1 ? W1 : W2);
    const float*    bia = (mat == 0) ? b0 : (mat == 1 ? b1 : b2);
    const int m0 = mt * 256, n0 = nt * 256;

    const int str = tid >> 3;
    const int sc8 = ((tid & 7) ^ (str & 7)) * 8;
    const _Float16* xsrc = X  + (size_t)(m0 + str) * D_MODEL + sc8;
    const _Float16* wsrc = Wm + (size_t)(n0 + str) * D_MODEL + sc8;
    const int ldst = str * 64 + (tid & 7) * 8;

#define SA(buf, kt, h) do { \
    gload16(xsrc + (size_t)((h) * 128) * D_MODEL + (kt) * 64, ABASE(buf) + (h) * 8192 + ldst); \
    gload16(xsrc + (size_t)((h) * 128 + 64) * D_MODEL + (kt) * 64, ABASE(buf) + (h) * 8192 + 4096 + ldst); } while (0)
#define SB(buf, kt, h) do { \
    gload16(wsrc + (size_t)((h) * 128) * D_MODEL + (kt) * 64, BBASE(buf) + (h) * 8192 + ldst); \
    gload16(wsrc + (size_t)((h) * 128 + 64) * D_MODEL + (kt) * 64, BBASE(buf) + (h) * 8192 + 4096 + ldst); } while (0)

    const int fr = l & 15, g = l >> 4, fr7 = l & 7;
    const int wrow = wr * 128, bcol = wc * 64;

    f32x4 acc[8][4] = {};
    f16x8 b[4][2];

    SB(0, 0, 0); SB(0, 0, 1);
    SA(0, 0, 0); SA(0, 0, 1);
    SB(1, 1, 0); SB(1, 1, 1);
    asm volatile("s_waitcnt vmcnt(4)" ::: "memory");
    __builtin_amdgcn_s_barrier();

#define PHASES(BUF, TSA_BUF, TSA, TSB_BUF, TSB)                                              \
    _Pragma("unroll")                                                                        \
    for (int p = 0; p < 4; ++p) {                                                            \
        if (p == 0) {                                                                        \
            _Pragma("unroll")                                                                \
            for (int nj = 0; nj < 4; ++nj) {                                                 \
                const int rb = (bcol + nj * 16 + fr) * 64;                                   \
                b[nj][0] = *(const f16x8*)&BBASE(BUF)[rb + ((g ^ fr7) << 3)];                \
                b[nj][1] = *(const f16x8*)&BBASE(BUF)[rb + (((4 + g) ^ fr7) << 3)];          \
            }                                                                                \
        }                                                                                    \
        f16x8 aq[2][2];                                                                      \
        _Pragma("unroll")                                                                    \
        for (int q = 0; q < 2; ++q) {                                                        \
            const int ra = (wrow + (2 * p + q) * 16 + fr) * 64;                              \
            aq[q][0] = *(const f16x8*)&ABASE(BUF)[ra + ((g ^ fr7) << 3)];                    \
            aq[q][1] = *(const f16x8*)&ABASE(BUF)[ra + (((4 + g) ^ fr7) << 3)];              \
        }                                                                                    \
        if (p == 0) SA(TSA_BUF, TSA, 0);                                                     \
        else if (p == 1) SA(TSA_BUF, TSA, 1);                                                \
        else if (p == 2) SB(TSB_BUF, TSB, 0);                                                \
        else SB(TSB_BUF, TSB, 1);                                                            \
        __builtin_amdgcn_s_barrier();                                                        \
        __builtin_amdgcn_s_setprio(1);                                                       \
        _Pragma("unroll")                                                                    \
        for (int ks = 0; ks < 2; ++ks)                                                       \
            _Pragma("unroll")                                                                \
            for (int q = 0; q < 2; ++q)                                                      \
                _Pragma("unroll")                                                            \
                for (int nj = 0; nj < 4; ++nj)                                               \
                    acc[2 * p + q][nj] = __builtin_amdgcn_mfma_f32_16x16x32_f16(             \
                        aq[q][ks], b[nj][ks], acc[2 * p + q][nj], 0, 0, 0);                  \
        __builtin_amdgcn_s_setprio(0);                                                       \
        if (p == 3) asm volatile("s_waitcnt vmcnt(4)" ::: "memory");                         \
        __builtin_amdgcn_s_barrier();                                                        \
    }

    for (int it = 0; it < 8; ++it) {
        const int tA = 2 * it + 1;
        const int tN = (2 * it + 2 < 16) ? 2 * it + 2 : 15;
        const int tM = (2 * it + 3 < 16) ? 2 * it + 3 : 15;
        PHASES(0, 1, tA, 0, tN)
        PHASES(1, 0, tN, 1, tM)
    }
#undef PHASES
#undef SA
#undef SB

    if (mat != 2) {
        const float scale = (mat == 0) ? 0.125f * 1.44269504088896340736f : 1.0f;
#pragma unroll
        for (int nj = 0; nj < 4; ++nj) {
            const int o = n0 + bcol + nj * 16 + fr;
            const float bb = bia[o];
            const int h = o >> 6, dd = o & 63;
#pragma unroll
            for (int mi = 0; mi < 8; ++mi) {
#pragma unroll
                for (int r = 0; r < 4; ++r) {
                    const int m = m0 + wrow + mi * 16 + g * 4 + r;
                    const int bi = m >> 10, s = m & 1023;
                    const float v = (acc[mi][nj][r] + bb) * scale;
                    const _Float16 hv = (_Float16)v;
                    const int bh = bi * NH + h;
                    if (mat == 0) Qo[((size_t)bh * SEQ + s) * DV + dd] = hv;
                    else          Ko[((size_t)bh * SEQ + s) * DV + dd] = hv;
                }
            }
        }
    } else {
        // V epilogue via LDS: transpose + coalesced 16B stores
        asm volatile("s_waitcnt vmcnt(0)" ::: "memory");
        __syncthreads();
#pragma unroll
        for (int nj = 0; nj < 4; ++nj) {
            const int n = bcol + nj * 16 + fr;
            const float bb = bia[n0 + n];
#pragma unroll
            for (int mi = 0; mi < 8; ++mi) {
#pragma unroll
                for (int r = 0; r < 4; ++r) {
                    const int m = wrow + mi * 16 + g * 4 + r;
                    SM[n * 256 + ((((m >> 3) + n) & 31) << 3) + (m & 7)] =
                        (_Float16)(acc[mi][nj][r] + bb);
                }
            }
        }
        __syncthreads();
        const int bi = m0 >> 10, s0 = m0 & 1023;
#pragma unroll
        for (int itp = 0; itp < 16; ++itp) {
            const int task = itp * 512 + tid;
            const int dd = task >> 5, sc = task & 31;
            f16x8 vv = *(const f16x8*)&SM[dd * 256 + (((sc + dd) & 31) << 3)];
            const int og = n0 + dd;
            const int h = og >> 6, d = og & 63;
            const int bh = bi * NH + h;
            *(f16x8*)(Vto + ((size_t)bh * DV + d) * SEQ + s0 + sc * 8) = vv;
        }
    }
#undef ABASE
#undef BBASE
}

// ---------------- flash attention v5: r6 structure + T15 cross-tile pipeline ----------------
// 8 waves/block, 16 q-rows/wave, K/V in a 3-deep LDS ring. Per body t:
// STAGE(t+1) ; QK(t) [MFMA pipe] ; softmax+PV(t-1) [VALU pipe + MFMA] ; vmcnt0+barrier.
// QK(t)'s MFMAs execute in the matrix pipe WHILE softmax(t-1)'s VALU chain runs ->
// the per-tile serial chain (QK->softmax->PV) is broken across tiles.
__global__ __launch_bounds__(512, 4) void attn(
    const _Float16* __restrict__ Q, const _Float16* __restrict__ K,
    const _Float16* __restrict__ Vt, float* __restrict__ out)
{
    __shared__ _Float16 Kb[3][64 * 64];   // 24KB ring
    __shared__ _Float16 Vb[3][64 * 64];   // 24KB ring
    __shared__ _Float16 P[8][16][80];     // 20KB, per-wave P slice

    const int tid = threadIdx.x;
    const int w = tid >> 6, l = tid & 63;
    const int qc = l & 15, g = l >> 4;

    // XCD swizzle: all 8 q-tiles of a head land on one XCD (512 % 8 == 0, bijective)
    const int fid = blockIdx.y * 8 + blockIdx.x;        // grid = (8, 64)
    const int nid = (fid & 7) * 64 + (fid >> 3);
    const int bh = nid >> 3, qt = nid & 7;
    const int b = bh >> 4, h = bh & 15;
    const int q0 = qt * QBLK + w * 16;

    // staging: thread covers row tid>>3, dest chunk tid&7, src chunk swizzled
    const int str = tid >> 3;
    const int scs = ((tid & 7) ^ (str & 7)) * 8;
    const int ldst = str * 64 + (tid & 7) * 8;
    const _Float16* Kg = K  + (size_t)bh * SEQ * DV;
    const _Float16* Vg = Vt + (size_t)bh * DV * SEQ;

    const _Float16* qp = Q + ((size_t)bh * SEQ + q0 + qc) * DV + g * 8;
    f16x8 qf0 = *(const f16x8*)(qp);
    f16x8 qf1 = *(const f16x8*)(qp + 32);

    float m_run = -1e30f, l_run = 0.f;
    f32x4 oacc[4] = {};
    const f32x4 zf = {0.f, 0.f, 0.f, 0.f};

#define STAGE(buf, kt) do {                                                    \
        gload16(Kg + (size_t)((kt) * 64 + str) * DV + scs, &Kb[buf][0] + ldst);\
        gload16(Vg + (size_t)str * SEQ + (kt) * 64 + scs, &Vb[buf][0] + ldst); \
    } while (0)

#define QK(S, kbuf) do {                                                                    \
        __builtin_amdgcn_s_setprio(1);                                                      \
        _Pragma("unroll")                                                                   \
        for (int kf = 0; kf < 4; ++kf) {                                                    \
            const int row = kf * 16 + qc;                                                   \
            f16x8 ka0 = *(const f16x8*)&Kb[kbuf][row * 64 + (((g)     ^ (qc & 7)) << 3)];   \
            f16x8 ka1 = *(const f16x8*)&Kb[kbuf][row * 64 + (((4 + g) ^ (qc & 7)) << 3)];   \
            f32x4 tt = __builtin_amdgcn_mfma_f32_16x16x32_f16(ka0, qf0, zf, 0, 0, 0);       \
            S[kf] = __builtin_amdgcn_mfma_f32_16x16x32_f16(ka1, qf1, tt, 0, 0, 0);          \
        }                                                                                   \
        __builtin_amdgcn_s_setprio(0);                                                      \
    } while (0)

#define SOFTPV(S, vbuf) do {                                                                \
        f32x4 mx = S[0];                                                                    \
        _Pragma("unroll")                                                                   \
        for (int kf = 1; kf < 4; ++kf)                                                      \
            _Pragma("unroll")                                                               \
            for (int r = 0; r < 4; ++r) mx[r] = fmaxf(mx[r], S[kf][r]);                     \
        float pmax = fmaxf(fmaxf(mx[0], mx[1]), fmaxf(mx[2], mx[3]));                       \
        pmax = fmaxf(pmax, __shfl_xor(pmax, 16));                                           \
        pmax = fmaxf(pmax, __shfl_xor(pmax, 32));                                           \
        if (!__all(pmax - m_run <= 8.0f)) {                                                 \
            const float mn = fmaxf(m_run, pmax);                                            \
            const float al = exp2f(m_run - mn);                                             \
            l_run *= al;                                                                    \
            _Pragma("unroll")                                                               \
            for (int df = 0; df < 4; ++df) oacc[df] *= al;                                  \
            m_run = mn;                                                                     \
        }                                                                                   \
        float rsum = 0.f;                                                                   \
        _Pragma("unroll")                                                                   \
        for (int kf = 0; kf < 4; ++kf) {                                                    \
            f16x4 ph;                                                                       \
            _Pragma("unroll")                                                               \
            for (int r = 0; r < 4; ++r) {                                                   \
                const float p = exp2f(S[kf][r] - m_run);                                    \
                rsum += p;                                                                  \
                ph[r] = (_Float16)p;                                                        \
            }                                                                               \
            *(f16x4*)&P[w][qc][kf * 16 + g * 4] = ph;                                       \
        }                                                                                   \
        rsum += __shfl_xor(rsum, 16);                                                       \
        rsum += __shfl_xor(rsum, 32);                                                       \
        l_run += rsum;                                                                      \
        __builtin_amdgcn_s_setprio(1);                                                      \
        _Pragma("unroll")                                                                   \
        for (int ks = 0; ks < 2; ++ks) {                                                    \
            f16x8 pb = *(const f16x8*)&P[w][qc][ks * 32 + g * 8];                           \
            _Pragma("unroll")                                                               \
            for (int df = 0; df < 4; ++df) {                                                \
                const int row = df * 16 + qc;                                               \
                f16x8 va = *(const f16x8*)&Vb[vbuf][row * 64 +                              \
                                                    (((ks * 4 + g) ^ (qc & 7)) << 3)];      \
                oacc[df] = __builtin_amdgcn_mfma_f32_16x16x32_f16(va, pb, oacc[df], 0,0,0); \
            }                                                                               \
        }                                                                                   \
        __builtin_amdgcn_s_setprio(0);                                                      \
    } while (0)

    f32x4 sA[4], sB[4];

    // prologue: tile 0 staged+computed (QK only), tile 1 staged
    STAGE(0, 0);
    asm volatile("s_waitcnt vmcnt(0)" ::: "memory");
    __syncthreads();
    STAGE(1, 1);
    QK(sA, 0);
    asm volatile("s_waitcnt vmcnt(0)" ::: "memory");
    __syncthreads();

#pragma unroll
    for (int it = 0; it < 7; ++it) {
        const int t1 = 2 * it + 1, t2 = 2 * it + 2;
        // body t1: cur = sB, prev = sA
        STAGE((t1 + 1) % 3, t1 + 1);
        QK(sB, t1 % 3);
        SOFTPV(sA, (t1 - 1) % 3);
        asm volatile("s_waitcnt vmcnt(0)" ::: "memory");
        __syncthreads();
        // body t2: cur = sA, prev = sB
        STAGE((t2 + 1) % 3, t2 + 1);
        QK(sA, t2 % 3);
        SOFTPV(sB, (t2 - 1) % 3);
        asm volatile("s_waitcnt vmcnt(0)" ::: "memory");
        __syncthreads();
    }
    // t = 15: cur = sB, prev = sA (no stage)
    QK(sB, 15 % 3);
    SOFTPV(sA, 14 % 3);
    // epilogue: finish tile 15 (same wave's P/V, no barrier needed)
    SOFTPV(sB, 15 % 3);

#undef STAGE
#undef QK
#undef SOFTPV

    const float inv = 1.0f / l_run;
    float* ob = out + ((size_t)b * SEQ + q0 + qc) * D_MODEL + h * DV;
#pragma unroll
    for (int df = 0; df < 4; ++df) {
        float4 v4;
        v4.x = oacc[df][0] * inv; v4.y = oacc[df][1] * inv;
        v4.z = oacc[df][2] * inv; v4.w = oacc[df][3] * inv;
        *(float4*)(ob + df * 16 + g * 4) = v4;
    }
}

extern "C" void kernel_launch(void* const* d_in, const int* in_sizes, int n_in,
                              void* d_out, int out_size, void* d_ws, size_t ws_size,
                              hipStream_t stream) {
    const float* seq = (const float*)d_in[0];
    const float* Wq  = (const float*)d_in[1];
    const float* bq  = (const float*)d_in[2];
    const float* Wk  = (const float*)d_in[3];
    const float* bk  = (const float*)d_in[4];
    const float* Wv  = (const float*)d_in[5];
    const float* bv  = (const float*)d_in[6];
    float* out = (float*)d_out;

    _Float16* seqh = (_Float16*)d_ws;
    _Float16* wqh  = seqh + (size_t)M_TOTAL * D_MODEL;
    _Float16* wkh  = wqh + (size_t)D_MODEL * D_MODEL;
    _Float16* wvh  = wkh + (size_t)D_MODEL * D_MODEL;
    _Float16* Qh   = wvh + (size_t)D_MODEL * D_MODEL;
    _Float16* Kh   = Qh + (size_t)M_TOTAL * D_MODEL;
    _Float16* Vth  = Kh + (size_t)M_TOTAL * D_MODEL;

    const int n_seq = M_TOTAL * D_MODEL;
    const int n_w   = D_MODEL * D_MODEL;
    cvt_f32_f16<<<n_seq / (256 * 8), 256, 0, stream>>>(seq, seqh, n_seq);
    cvt3_f32_f16<<<dim3(n_w / (256 * 8), 3), 256, 0, stream>>>(Wq, Wk, Wv, wqh, wkh, wvh, n_w);

    qkv_gemm<<<192, 512, 0, stream>>>(
        seqh, wqh, wkh, wvh, bq, bk, bv, Qh, Kh, Vth);

    attn<<<dim3(SEQ / QBLK, BATCH * NH), 512, 0, stream>>>(Qh, Kh, Vth, out);
}